// Round 1
// baseline (40007.529 us; speedup 1.0000x reference)
//
#include <hip/hip_runtime.h>
#include <hip/hip_cooperative_groups.h>

namespace cg = cooperative_groups;

#define H 1024
#define T 4096
#define NBLK 64          // 64 workgroups -> guaranteed co-resident on 256 CUs
#define TPB 1024         // 16 waves per WG, one wave per hidden unit
#define WAVES_PER_BLK (TPB / 64)
#define SOLVE_ITERS 64   // Richardson iters for h0 = A^{-1}(u0-c); rho~0.64 -> ~1e-12

__device__ __forceinline__ float sigmoidf_(float x) {
    return 1.0f / (1.0f + __expf(-x));
}
__device__ __forceinline__ float tanh_fast_(float x) {
    // tanh(x) = 2*sigmoid(2x) - 1 ; saturates correctly for large |x|
    return 2.0f * sigmoidf_(2.0f * x) - 1.0f;
}

// Persistent cooperative kernel: phase 0 = iterative solve for h0,
// phase 1 = 4095 sequential GRU steps. hs rows are written into `out`
// (row t = h_t); the obs affine map is applied in-place by obs_kernel after.
__global__ __launch_bounds__(TPB, 1) void rnn_kernel(
    const float* __restrict__ u0,
    const float* __restrict__ W_hh,
    const float* __restrict__ b_ih,
    const float* __restrict__ b_hh,
    const float* __restrict__ A,
    const float* __restrict__ c,
    float* __restrict__ out,
    float* __restrict__ hbuf)        // workspace: 2*H floats (double buffer)
{
    cg::grid_group grid = cg::this_grid();
    __shared__ float hlds[H];

    const int tid  = threadIdx.x;
    const int wave = tid >> 6;
    const int lane = tid & 63;
    const int j    = blockIdx.x * WAVES_PER_BLK + wave;   // hidden unit 0..1023

    // Preload W_hh rows (r,z,n) for unit j in stride-64 layout:
    // w[k] = row[lane + 64*k]  -> global loads coalesced, LDS h reads 2-way (free)
    float wr[16], wz[16], wn[16];
    {
        const float* pr = W_hh + (size_t)j * H;
        const float* pz = W_hh + (size_t)(H + j) * H;
        const float* pn = W_hh + (size_t)(2 * H + j) * H;
#pragma unroll
        for (int k = 0; k < 16; ++k) {
            wr[k] = pr[lane + 64 * k];
            wz[k] = pz[lane + 64 * k];
            wn[k] = pn[lane + 64 * k];
        }
    }
    // control = zeros -> input gates are just b_ih
    const float br  = b_ih[j]         + b_hh[j];
    const float bz  = b_ih[H + j]     + b_hh[H + j];
    const float bin = b_ih[2 * H + j];
    const float bhn = b_hh[2 * H + j];
    const float bj  = u0[j] - c[j];   // rhs of A h0 = u0 - c

    // ---- Phase 0: h0 via Richardson iteration  h <- b + h - A h ----
    if (lane == 0) hbuf[j] = bj;      // initial guess h = b, buffer 0
    grid.sync();
    int cur = 0;
    const float* arow = A + (size_t)j * H;
    for (int it = 0; it < SOLVE_ITERS; ++it) {
        hlds[tid] = hbuf[cur * H + tid];
        __syncthreads();
        float acc = 0.f;
#pragma unroll
        for (int k = 0; k < 16; ++k)
            acc += arow[lane + 64 * k] * hlds[lane + 64 * k];
#pragma unroll
        for (int m = 32; m >= 1; m >>= 1)
            acc += __shfl_xor(acc, m, 64);
        if (lane == 0) hbuf[(cur ^ 1) * H + j] = bj + hlds[j] - acc;
        cur ^= 1;
        grid.sync();
    }

    // hs row 0 = h0
    if (lane == 0) out[j] = hbuf[cur * H + j];

    // ---- Phase 1: GRU recurrence, 4095 steps ----
    for (int t = 1; t < T; ++t) {
        hlds[tid] = hbuf[cur * H + tid];
        __syncthreads();
        float ar = 0.f, az = 0.f, an = 0.f;
#pragma unroll
        for (int k = 0; k < 16; ++k) {
            const float hv = hlds[lane + 64 * k];
            ar += wr[k] * hv;
            az += wz[k] * hv;
            an += wn[k] * hv;
        }
#pragma unroll
        for (int m = 32; m >= 1; m >>= 1) {
            ar += __shfl_xor(ar, m, 64);
            az += __shfl_xor(az, m, 64);
            an += __shfl_xor(an, m, 64);
        }
        if (lane == 0) {
            const float r  = sigmoidf_(br + ar);
            const float z  = sigmoidf_(bz + az);
            const float n  = tanh_fast_(bin + r * (an + bhn));
            const float hj = hlds[j];
            const float hn2 = (1.f - z) * n + z * hj;
            hbuf[(cur ^ 1) * H + j] = hn2;
            out[(size_t)t * H + j]  = hn2;
        }
        cur ^= 1;
        grid.sync();
    }
}

// In-place affine map: out[t] <- A @ out[t] + c, 16 rows per WG.
// All LDS reads in the hot loop are wave-broadcast (same addr) -> conflict-free.
#define RT 16
__global__ __launch_bounds__(256, 1) void obs_kernel(
    const float* __restrict__ A,
    const float* __restrict__ c,
    float* __restrict__ out)
{
    __shared__ float hl[RT][H];      // 64 KiB
    const int tid = threadIdx.x;
    const int r0  = blockIdx.x * RT;

    {
        const float4* src = (const float4*)(out + (size_t)r0 * H);
        float4* dst = (float4*)(&hl[0][0]);
        for (int i = tid; i < RT * H / 4; i += 256)
            dst[i] = src[i];
    }
    __syncthreads();

    float acc[4][RT];
#pragma unroll
    for (int s = 0; s < 4; ++s) {
        const float cv = c[tid + 256 * s];
#pragma unroll
        for (int t = 0; t < RT; ++t) acc[s][t] = cv;
    }
    const float* a0 = A + (size_t)(tid      ) * H;
    const float* a1 = A + (size_t)(tid + 256) * H;
    const float* a2 = A + (size_t)(tid + 512) * H;
    const float* a3 = A + (size_t)(tid + 768) * H;

    for (int jj = 0; jj < H; jj += 4) {
        const float4 v0 = *(const float4*)(a0 + jj);
        const float4 v1 = *(const float4*)(a1 + jj);
        const float4 v2 = *(const float4*)(a2 + jj);
        const float4 v3 = *(const float4*)(a3 + jj);
#pragma unroll
        for (int t = 0; t < RT; ++t) {
            const float h0v = hl[t][jj];
            const float h1v = hl[t][jj + 1];
            const float h2v = hl[t][jj + 2];
            const float h3v = hl[t][jj + 3];
            acc[0][t] += v0.x * h0v + v0.y * h1v + v0.z * h2v + v0.w * h3v;
            acc[1][t] += v1.x * h0v + v1.y * h1v + v1.z * h2v + v1.w * h3v;
            acc[2][t] += v2.x * h0v + v2.y * h1v + v2.z * h2v + v2.w * h3v;
            acc[3][t] += v3.x * h0v + v3.y * h1v + v3.z * h2v + v3.w * h3v;
        }
    }
#pragma unroll
    for (int s = 0; s < 4; ++s)
#pragma unroll
        for (int t = 0; t < RT; ++t)
            out[(size_t)(r0 + t) * H + tid + 256 * s] = acc[s][t];
}

extern "C" void kernel_launch(void* const* d_in, const int* in_sizes, int n_in,
                              void* d_out, int out_size, void* d_ws, size_t ws_size,
                              hipStream_t stream) {
    // inputs: 0 ts, 1 u0, 2 W_ih (unused: control==0), 3 W_hh, 4 b_ih,
    //         5 b_hh, 6 A, 7 c
    const float* u0   = (const float*)d_in[1];
    const float* W_hh = (const float*)d_in[3];
    const float* b_ih = (const float*)d_in[4];
    const float* b_hh = (const float*)d_in[5];
    const float* A    = (const float*)d_in[6];
    const float* c    = (const float*)d_in[7];
    float* out  = (float*)d_out;
    float* hbuf = (float*)d_ws;      // 2*H floats used

    void* args[] = { (void*)&u0, (void*)&W_hh, (void*)&b_ih, (void*)&b_hh,
                     (void*)&A, (void*)&c, (void*)&out, (void*)&hbuf };
    hipLaunchCooperativeKernel((const void*)rnn_kernel, dim3(NBLK), dim3(TPB),
                               args, 0, stream);
    hipLaunchKernelGGL(obs_kernel, dim3(T / RT), dim3(256), 0, stream,
                       A, c, out);
}

// Round 2
// 16960.178 us; speedup vs baseline: 2.3589x; 2.3589x over previous
//
#include <hip/hip_runtime.h>

#define H 1024
#define T 4096
#define G 64            // producer blocks, one CU each, 16 hidden units per block
#define TPB 1024        // 16 waves per block, 1 hidden unit per wave
#define WPB (TPB / 64)
#define SOLVE_ITERS 48  // Richardson: rho ~ 0.64 -> 0.64^48 ~ 5e-10

#define SCOPE __HIP_MEMORY_SCOPE_AGENT

__device__ __forceinline__ float sigmoidf_(float x) {
    return 1.0f / (1.0f + __expf(-x));
}
__device__ __forceinline__ float tanh_fast_(float x) {
    return 2.0f * sigmoidf_(2.0f * x) - 1.0f;
}

// ws layout: scnt[64] (solve counters), cnt[T] (step counters), sbuf[2*H] floats
__global__ __launch_bounds__(256) void init_kernel(int* flags, int n) {
    int i = blockIdx.x * 256 + threadIdx.x;
    if (i < n) flags[i] = 0;
}

// Persistent producer/consumer kernel. No grid.sync: per-step release counter
// + acquire spin. h rows live in `out` (row t = h_t), so no back-pressure.
__global__ __launch_bounds__(TPB, 4) void rnn_kernel(
    const float* __restrict__ u0,
    const float* __restrict__ W_hh,
    const float* __restrict__ b_ih,
    const float* __restrict__ b_hh,
    const float* __restrict__ A,
    const float* __restrict__ c,
    float* __restrict__ out,
    int* __restrict__ ws_i)
{
    __shared__ float hlds[H];

    const int tid  = threadIdx.x;
    const int lane = tid & 63;
    const int wave = tid >> 6;
    const int j    = blockIdx.x * WPB + wave;   // hidden unit 0..1023

    int* scnt   = ws_i;
    int* cnt    = ws_i + 64;
    float* sbuf = (float*)(cnt + T);

    // ---- preload weights (stride-64 k-split: w[k] corresponds to h[lane+64k]) ----
    float wr[16], wz[16], wn[16], av[16];
    {
        const float* pr = W_hh + (size_t)j * H;
        const float* pz = W_hh + (size_t)(H + j) * H;
        const float* pn = W_hh + (size_t)(2 * H + j) * H;
        const float* pa = A + (size_t)j * H;
#pragma unroll
        for (int k = 0; k < 16; ++k) {
            wr[k] = pr[lane + 64 * k];
            wz[k] = pz[lane + 64 * k];
            wn[k] = pn[lane + 64 * k];
            av[k] = pa[lane + 64 * k];
        }
    }
    const float br  = b_ih[j]         + b_hh[j];
    const float bz  = b_ih[H + j]     + b_hh[H + j];
    const float bin = b_ih[2 * H + j];
    const float bhn = b_hh[2 * H + j];
    const float bj  = u0[j] - c[j];   // rhs of A h0 = u0 - c

    // ---- Phase 0: publish iterate 0 (h = b) ----
    if (lane == 0)
        __hip_atomic_store(&sbuf[j], bj, __ATOMIC_RELAXED, SCOPE);
    __syncthreads();
    if (tid == 0)
        __hip_atomic_fetch_add(&scnt[0], 1, __ATOMIC_RELEASE, SCOPE);

    // ---- Richardson iterations: h_r = b + h_{r-1} - A h_{r-1} ----
    for (int r = 1; r <= SOLVE_ITERS; ++r) {
        if (tid == 0) {
            while (__hip_atomic_load(&scnt[r - 1], __ATOMIC_ACQUIRE, SCOPE) < G) {}
        }
        __syncthreads();
        const float* src = sbuf + ((r - 1) & 1) * H;
        hlds[tid] = __hip_atomic_load(&src[tid], __ATOMIC_RELAXED, SCOPE);
        __syncthreads();

        float hv[16];
#pragma unroll
        for (int k = 0; k < 16; ++k) hv[k] = hlds[lane + 64 * k];
        float acc = 0.f;
#pragma unroll
        for (int k = 0; k < 16; ++k) acc += av[k] * hv[k];
#pragma unroll
        for (int m = 32; m >= 1; m >>= 1) acc += __shfl_xor(acc, m, 64);

        if (lane == 0) {
            const float hn = bj + hlds[j] - acc;
            if (r == SOLVE_ITERS)
                __hip_atomic_store(&out[j], hn, __ATOMIC_RELAXED, SCOPE);
            else
                __hip_atomic_store(&sbuf[(r & 1) * H + j], hn, __ATOMIC_RELAXED, SCOPE);
        }
        __syncthreads();
        if (tid == 0) {
            int* flag = (r == SOLVE_ITERS) ? &cnt[0] : &scnt[r];
            __hip_atomic_fetch_add(flag, 1, __ATOMIC_RELEASE, SCOPE);
        }
    }

    // ---- Phase 1: GRU recurrence, 4095 steps ----
    for (int t = 1; t < T; ++t) {
        if (tid == 0) {
            while (__hip_atomic_load(&cnt[t - 1], __ATOMIC_ACQUIRE, SCOPE) < G) {}
        }
        __syncthreads();
        hlds[tid] = __hip_atomic_load(&out[(size_t)(t - 1) * H + tid],
                                      __ATOMIC_RELAXED, SCOPE);
        __syncthreads();

        float hv[16];
#pragma unroll
        for (int k = 0; k < 16; ++k) hv[k] = hlds[lane + 64 * k];
        float ar = 0.f, az = 0.f, an = 0.f;
#pragma unroll
        for (int k = 0; k < 16; ++k) {
            ar += wr[k] * hv[k];
            az += wz[k] * hv[k];
            an += wn[k] * hv[k];
        }
#pragma unroll
        for (int m = 32; m >= 1; m >>= 1) {
            ar += __shfl_xor(ar, m, 64);
            az += __shfl_xor(az, m, 64);
            an += __shfl_xor(an, m, 64);
        }
        if (lane == 0) {
            const float r2 = sigmoidf_(br + ar);
            const float z2 = sigmoidf_(bz + az);
            const float n2 = tanh_fast_(bin + r2 * (an + bhn));
            const float hn2 = (1.f - z2) * n2 + z2 * hlds[j];
            __hip_atomic_store(&out[(size_t)t * H + j], hn2, __ATOMIC_RELAXED, SCOPE);
        }
        __syncthreads();
        if (tid == 0)
            __hip_atomic_fetch_add(&cnt[t], 1, __ATOMIC_RELEASE, SCOPE);
    }
}

// In-place affine map: out[t] <- A @ out[t] + c, 16 rows per WG.
#define RT 16
__global__ __launch_bounds__(256, 1) void obs_kernel(
    const float* __restrict__ A,
    const float* __restrict__ c,
    float* __restrict__ out)
{
    __shared__ float hl[RT][H];      // 64 KiB
    const int tid = threadIdx.x;
    const int r0  = blockIdx.x * RT;

    {
        const float4* src = (const float4*)(out + (size_t)r0 * H);
        float4* dst = (float4*)(&hl[0][0]);
        for (int i = tid; i < RT * H / 4; i += 256)
            dst[i] = src[i];
    }
    __syncthreads();

    float acc[4][RT];
#pragma unroll
    for (int s = 0; s < 4; ++s) {
        const float cv = c[tid + 256 * s];
#pragma unroll
        for (int t = 0; t < RT; ++t) acc[s][t] = cv;
    }
    const float* a0 = A + (size_t)(tid      ) * H;
    const float* a1 = A + (size_t)(tid + 256) * H;
    const float* a2 = A + (size_t)(tid + 512) * H;
    const float* a3 = A + (size_t)(tid + 768) * H;

    for (int jj = 0; jj < H; jj += 4) {
        const float4 v0 = *(const float4*)(a0 + jj);
        const float4 v1 = *(const float4*)(a1 + jj);
        const float4 v2 = *(const float4*)(a2 + jj);
        const float4 v3 = *(const float4*)(a3 + jj);
#pragma unroll
        for (int t = 0; t < RT; ++t) {
            const float h0v = hl[t][jj];
            const float h1v = hl[t][jj + 1];
            const float h2v = hl[t][jj + 2];
            const float h3v = hl[t][jj + 3];
            acc[0][t] += v0.x * h0v + v0.y * h1v + v0.z * h2v + v0.w * h3v;
            acc[1][t] += v1.x * h0v + v1.y * h1v + v1.z * h2v + v1.w * h3v;
            acc[2][t] += v2.x * h0v + v2.y * h1v + v2.z * h2v + v2.w * h3v;
            acc[3][t] += v3.x * h0v + v3.y * h1v + v3.z * h2v + v3.w * h3v;
        }
    }
#pragma unroll
    for (int s = 0; s < 4; ++s)
#pragma unroll
        for (int t = 0; t < RT; ++t)
            out[(size_t)(r0 + t) * H + tid + 256 * s] = acc[s][t];
}

extern "C" void kernel_launch(void* const* d_in, const int* in_sizes, int n_in,
                              void* d_out, int out_size, void* d_ws, size_t ws_size,
                              hipStream_t stream) {
    // inputs: 0 ts, 1 u0, 2 W_ih (unused: control==0), 3 W_hh, 4 b_ih,
    //         5 b_hh, 6 A, 7 c
    const float* u0   = (const float*)d_in[1];
    const float* W_hh = (const float*)d_in[3];
    const float* b_ih = (const float*)d_in[4];
    const float* b_hh = (const float*)d_in[5];
    const float* A    = (const float*)d_in[6];
    const float* c    = (const float*)d_in[7];
    float* out  = (float*)d_out;
    int*   wsp  = (int*)d_ws;

    const int nflags = 64 + T;
    hipLaunchKernelGGL(init_kernel, dim3((nflags + 255) / 256), dim3(256), 0,
                       stream, wsp, nflags);

    void* args[] = { (void*)&u0, (void*)&W_hh, (void*)&b_ih, (void*)&b_hh,
                     (void*)&A, (void*)&c, (void*)&out, (void*)&wsp };
    hipLaunchCooperativeKernel((const void*)rnn_kernel, dim3(G), dim3(TPB),
                               args, 0, stream);
    hipLaunchKernelGGL(obs_kernel, dim3(T / RT), dim3(256), 0, stream,
                       A, c, out);
}

// Round 3
// 14544.835 us; speedup vs baseline: 2.7506x; 1.1661x over previous
//
#include <hip/hip_runtime.h>

#define H 1024
#define T 4096
#define G 64            // producer blocks; block b owns hidden units [16b, 16b+16)
#define TPB 1024        // 16 waves per block, one hidden unit per wave
#define WPB 16
#define SOLVE_ITERS 48  // Richardson: rho ~ 0.64 -> 0.64^48 ~ 5e-10

#define SCOPE __HIP_MEMORY_SCOPE_AGENT

__device__ __forceinline__ float sigmoidf_(float x) {
    return 1.0f / (1.0f + __expf(-x));
}
__device__ __forceinline__ float tanh_fast_(float x) {
    return 2.0f * sigmoidf_(2.0f * x) - 1.0f;
}

// Publish h[j] for epoch e: one 8-byte single-copy-atomic store packing the
// value with an epoch-salted check word. Poison (0xAA..) gives lo^hi==0 which
// never equals ~e; stale epoch e-2 pairs give ~(e-2) != ~e. So the data IS
// the barrier: no flags, no fences, no init, no RMW atomics.
__device__ __forceinline__ void publish_(unsigned long long* pbuf, int e, int j, float v) {
    const unsigned lo = __float_as_uint(v);
    const unsigned hi = lo ^ ~(unsigned)e;
    const unsigned long long pk = ((unsigned long long)hi << 32) | lo;
    __hip_atomic_store(&pbuf[(size_t)(e & 1) * H + j], pk, __ATOMIC_RELAXED, SCOPE);
}

__global__ __launch_bounds__(TPB) void rnn_kernel(
    const float* __restrict__ u0,
    const float* __restrict__ W_hh,
    const float* __restrict__ b_ih,
    const float* __restrict__ b_hh,
    const float* __restrict__ A,
    const float* __restrict__ c,
    float* __restrict__ out,
    unsigned long long* __restrict__ pbuf)   // ws: 2*H u64 = 16 KB
{
    __shared__ float hlds[2][H];             // double-buffered by epoch parity

    const int tid  = threadIdx.x;
    const int lane = tid & 63;
    const int wave = tid >> 6;
    const int j    = blockIdx.x * WPB + wave;   // hidden unit 0..1023

    // ---- preload weights, stride-64 k-split: w[k] pairs with h[lane+64k] ----
    float wr[16], wz[16], wn[16], av[16];
    {
        const float* pr = W_hh + (size_t)j * H;
        const float* pz = W_hh + (size_t)(H + j) * H;
        const float* pn = W_hh + (size_t)(2 * H + j) * H;
        const float* pa = A + (size_t)j * H;
#pragma unroll
        for (int k = 0; k < 16; ++k) {
            wr[k] = pr[lane + 64 * k];
            wz[k] = pz[lane + 64 * k];
            wn[k] = pn[lane + 64 * k];
            av[k] = pa[lane + 64 * k];
        }
    }
    const float br  = b_ih[j]         + b_hh[j];
    const float bz  = b_ih[H + j]     + b_hh[H + j];
    const float bin = b_ih[2 * H + j];
    const float bhn = b_hh[2 * H + j];
    const float bj  = u0[j] - c[j];   // rhs of A h0 = u0 - c

    // ---- epoch 0: publish Richardson iterate 0 (h = b) ----
    if (lane == 0) publish_(pbuf, 0, j, bj);

    // ---- solve epochs 1..48: h_r = b + h_{r-1} - A h_{r-1} ----
    for (int r = 1; r <= SOLVE_ITERS; ++r) {
        const int p = (r - 1) & 1;
        const unsigned salt = ~(unsigned)(r - 1);
        unsigned long long pk;
        do {
            pk = __hip_atomic_load(&pbuf[(size_t)p * H + tid], __ATOMIC_RELAXED, SCOPE);
        } while ((((unsigned)(pk >> 32)) ^ (unsigned)pk) != salt);
        hlds[p][tid] = __uint_as_float((unsigned)pk);
        __syncthreads();

        float acc = 0.f;
#pragma unroll
        for (int k = 0; k < 16; ++k) acc += av[k] * hlds[p][lane + 64 * k];
#pragma unroll
        for (int m = 32; m >= 1; m >>= 1) acc += __shfl_xor(acc, m, 64);

        if (lane == 0) {
            const float hn = bj + hlds[p][j] - acc;
            publish_(pbuf, r, j, hn);
            if (r == SOLVE_ITERS) out[j] = hn;   // hs row 0 = h0
        }
    }

    // ---- GRU epochs: step t consumes epoch 48+t-1, publishes 48+t ----
    for (int t = 1; t < T; ++t) {
        const int e = SOLVE_ITERS + t;
        const int p = (e - 1) & 1;
        const unsigned salt = ~(unsigned)(e - 1);
        unsigned long long pk;
        do {
            pk = __hip_atomic_load(&pbuf[(size_t)p * H + tid], __ATOMIC_RELAXED, SCOPE);
        } while ((((unsigned)(pk >> 32)) ^ (unsigned)pk) != salt);
        hlds[p][tid] = __uint_as_float((unsigned)pk);
        __syncthreads();

        float hv[16];
#pragma unroll
        for (int k = 0; k < 16; ++k) hv[k] = hlds[p][lane + 64 * k];
        float ar = 0.f, az = 0.f, an = 0.f;
#pragma unroll
        for (int k = 0; k < 16; ++k) {
            ar += wr[k] * hv[k];
            az += wz[k] * hv[k];
            an += wn[k] * hv[k];
        }
#pragma unroll
        for (int m = 32; m >= 1; m >>= 1) {
            ar += __shfl_xor(ar, m, 64);
            az += __shfl_xor(az, m, 64);
            an += __shfl_xor(an, m, 64);
        }
        if (lane == 0) {
            const float r2  = sigmoidf_(br + ar);
            const float z2  = sigmoidf_(bz + az);
            const float n2  = tanh_fast_(bin + r2 * (an + bhn));
            const float hn2 = (1.f - z2) * n2 + z2 * hlds[p][j];
            publish_(pbuf, e, j, hn2);
            out[(size_t)t * H + j] = hn2;        // plain store; read post-kernel
        }
    }
}

// In-place affine map: out[t] <- A @ out[t] + c, 16 rows per WG.
#define RT 16
__global__ __launch_bounds__(256, 1) void obs_kernel(
    const float* __restrict__ A,
    const float* __restrict__ c,
    float* __restrict__ out)
{
    __shared__ float hl[RT][H];      // 64 KiB
    const int tid = threadIdx.x;
    const int r0  = blockIdx.x * RT;

    {
        const float4* src = (const float4*)(out + (size_t)r0 * H);
        float4* dst = (float4*)(&hl[0][0]);
        for (int i = tid; i < RT * H / 4; i += 256)
            dst[i] = src[i];
    }
    __syncthreads();

    float acc[4][RT];
#pragma unroll
    for (int s = 0; s < 4; ++s) {
        const float cv = c[tid + 256 * s];
#pragma unroll
        for (int t = 0; t < RT; ++t) acc[s][t] = cv;
    }
    const float* a0 = A + (size_t)(tid      ) * H;
    const float* a1 = A + (size_t)(tid + 256) * H;
    const float* a2 = A + (size_t)(tid + 512) * H;
    const float* a3 = A + (size_t)(tid + 768) * H;

    for (int jj = 0; jj < H; jj += 4) {
        const float4 v0 = *(const float4*)(a0 + jj);
        const float4 v1 = *(const float4*)(a1 + jj);
        const float4 v2 = *(const float4*)(a2 + jj);
        const float4 v3 = *(const float4*)(a3 + jj);
#pragma unroll
        for (int t = 0; t < RT; ++t) {
            const float h0v = hl[t][jj];
            const float h1v = hl[t][jj + 1];
            const float h2v = hl[t][jj + 2];
            const float h3v = hl[t][jj + 3];
            acc[0][t] += v0.x * h0v + v0.y * h1v + v0.z * h2v + v0.w * h3v;
            acc[1][t] += v1.x * h0v + v1.y * h1v + v1.z * h2v + v1.w * h3v;
            acc[2][t] += v2.x * h0v + v2.y * h1v + v2.z * h2v + v2.w * h3v;
            acc[3][t] += v3.x * h0v + v3.y * h1v + v3.z * h2v + v3.w * h3v;
        }
    }
#pragma unroll
    for (int s = 0; s < 4; ++s)
#pragma unroll
        for (int t = 0; t < RT; ++t)
            out[(size_t)(r0 + t) * H + tid + 256 * s] = acc[s][t];
}

extern "C" void kernel_launch(void* const* d_in, const int* in_sizes, int n_in,
                              void* d_out, int out_size, void* d_ws, size_t ws_size,
                              hipStream_t stream) {
    // inputs: 0 ts, 1 u0, 2 W_ih (unused: control==0), 3 W_hh, 4 b_ih,
    //         5 b_hh, 6 A, 7 c
    const float* u0   = (const float*)d_in[1];
    const float* W_hh = (const float*)d_in[3];
    const float* b_ih = (const float*)d_in[4];
    const float* b_hh = (const float*)d_in[5];
    const float* A    = (const float*)d_in[6];
    const float* c    = (const float*)d_in[7];
    float* out = (float*)d_out;
    unsigned long long* pbuf = (unsigned long long*)d_ws;  // 16 KB used

    void* args[] = { (void*)&u0, (void*)&W_hh, (void*)&b_ih, (void*)&b_hh,
                     (void*)&A, (void*)&c, (void*)&out, (void*)&pbuf };
    hipLaunchCooperativeKernel((const void*)rnn_kernel, dim3(G), dim3(TPB),
                               args, 0, stream);
    hipLaunchKernelGGL(obs_kernel, dim3(T / RT), dim3(256), 0, stream,
                       A, c, out);
}